// Round 4
// baseline (235.607 us; speedup 1.0000x reference)
//
#include <hip/hip_runtime.h>

typedef unsigned short u16;
typedef unsigned int u32;
typedef __attribute__((ext_vector_type(8))) short bf16x8;
typedef __attribute__((ext_vector_type(4))) float f32x4;

#define DIM 256
#define NOUT 512
#define MROWS 32768
#define NNODE 32768
#define NEDGE (256*128*128)
#define PARAM_SZ (32768*512)
#define GEMM_BLOCKS 512            // MROWS / 64  (64x128 wave tile)
#define EDGE_BLOCKS 4096           // NEDGE / 1024 (4 edges/thread)

__device__ __forceinline__ u16 f2bf(float f) {
    u32 x = __float_as_uint(f);
    u32 r = (x + 0x7FFFu + ((x >> 16) & 1u)) >> 16;   // round-to-nearest-even
    return (u16)r;
}
__device__ __forceinline__ float bf2f(u16 u) {
    union { u32 i; float f; } v; v.i = ((u32)u) << 16; return v.f;
}

// ================= prep: Wt transpose + x float4-pack + emb bf16-pad, one dispatch =======
__global__ __launch_bounds__(256) void prep_kernel(const float* __restrict__ W,
                                                   const float* __restrict__ x,
                                                   const float* __restrict__ emb,
                                                   u16* __restrict__ Wt,
                                                   float4* __restrict__ xp,
                                                   u16* __restrict__ embp) {
    const int b = blockIdx.x;
    const int tid = threadIdx.x;
    if (b < 128) {
        __shared__ u16 tile[32][33];
        int k0 = (b >> 4) * 32;            // K: 256 -> 8
        int n0 = (b & 15) * 32;            // N: 512 -> 16
        int tx = tid & 31, ty0 = tid >> 5; // 8 rows/pass, 4 passes
        #pragma unroll
        for (int j = 0; j < 4; ++j) {
            int ty = ty0 + j * 8;
            tile[ty][tx] = f2bf(W[(k0 + ty) * NOUT + n0 + tx]);
        }
        __syncthreads();
        #pragma unroll
        for (int j = 0; j < 4; ++j) {
            int ty = ty0 + j * 8;
            Wt[(n0 + ty) * DIM + k0 + tx] = tile[tx][ty];
        }
    } else if (b < 256) {
        int i = (b - 128) * 256 + tid;     // 32768 nodes
        float4 v;
        v.x = x[i * 3 + 0]; v.y = x[i * 3 + 1]; v.z = x[i * 3 + 2]; v.w = 0.0f;
        xp[i] = v;
    } else {
        int i = (b - 256) * 256 + tid;     // 100*256 = 25600 entries
        int col = i & 255;
        int row = i >> 8;
        embp[i] = (col == 0) ? (u16)0 : f2bf(emb[row * 255 + col - 1]);
    }
}

// L1-bypass gather: 8 agent-scope (sc0) dwordx4 loads in one asm block.
__device__ __forceinline__ void gather8_sc0(const float4* p0, const float4* p1,
                                            const float4* p2, const float4* p3,
                                            const float4* p4, const float4* p5,
                                            const float4* p6, const float4* p7,
                                            f32x4& a0, f32x4& a1, f32x4& a2, f32x4& a3,
                                            f32x4& b0, f32x4& b1, f32x4& b2, f32x4& b3) {
    asm volatile(
        "global_load_dwordx4 %0, %8, off sc0\n\t"
        "global_load_dwordx4 %1, %9, off sc0\n\t"
        "global_load_dwordx4 %2, %10, off sc0\n\t"
        "global_load_dwordx4 %3, %11, off sc0\n\t"
        "global_load_dwordx4 %4, %12, off sc0\n\t"
        "global_load_dwordx4 %5, %13, off sc0\n\t"
        "global_load_dwordx4 %6, %14, off sc0\n\t"
        "global_load_dwordx4 %7, %15, off sc0\n\t"
        "s_waitcnt vmcnt(0)"
        : "=&v"(a0), "=&v"(a1), "=&v"(a2), "=&v"(a3),
          "=&v"(b0), "=&v"(b1), "=&v"(b2), "=&v"(b3)
        : "v"(p0), "v"(p1), "v"(p2), "v"(p3), "v"(p4), "v"(p5), "v"(p6), "v"(p7)
        : "memory");
}

// ================= edge kernel: standalone (own small reg/LDS footprint) ================
__global__ __launch_bounds__(256) void edge_kernel(const int* __restrict__ edges,
                                                   const float4* __restrict__ xp,
                                                   float* __restrict__ radial_out,
                                                   float* __restrict__ cd_out) {
    __shared__ float buf[3072];                  // 12 KB
    const int eb = blockIdx.x;
    const int tid = threadIdx.x;
    const int t4 = eb * 256 + tid;               // index into int4-edge arrays
    int4 r4 = ((const int4*)edges)[t4];
    int4 c4 = ((const int4*)(edges + NEDGE))[t4];

    f32x4 xr0, xr1, xr2, xr3, xc0, xc1, xc2, xc3;
    gather8_sc0(xp + r4.x, xp + r4.y, xp + r4.z, xp + r4.w,
                xp + c4.x, xp + c4.y, xp + c4.z, xp + c4.w,
                xr0, xr1, xr2, xr3, xc0, xc1, xc2, xc3);

    f32x4 rad;
    float cdv[12];
    #pragma unroll
    for (int e = 0; e < 4; ++e) {
        f32x4 a = (e == 0) ? xr0 : (e == 1) ? xr1 : (e == 2) ? xr2 : xr3;
        f32x4 b = (e == 0) ? xc0 : (e == 1) ? xc1 : (e == 2) ? xc2 : xc3;
        float dx = a.x - b.x, dy = a.y - b.y, dz = a.z - b.z;
        float r = dx * dx + dy * dy + dz * dz;
        float inv = 1.0f / (sqrtf(r + 1e-8f) + 1.0f);   // norm + norm_constant(1.0)
        rad[e] = r;
        cdv[e * 3 + 0] = dx * inv;
        cdv[e * 3 + 1] = dy * inv;
        cdv[e * 3 + 2] = dz * inv;
    }
    __builtin_nontemporal_store(rad, ((f32x4*)radial_out) + t4);

    // repack coord_diff [1024,3] through LDS -> dense float4 global stores
    #pragma unroll
    for (int k = 0; k < 3; ++k)
        ((f32x4*)buf)[tid * 3 + k] = ((const f32x4*)cdv)[k];   // 2-way alias: free
    __syncthreads();
    f32x4* cdg = (f32x4*)(cd_out + (size_t)eb * 3072);
    #pragma unroll
    for (int k = 0; k < 3; ++k)
        __builtin_nontemporal_store(((const f32x4*)buf)[k * 256 + tid], cdg + k * 256 + tid);
}

// ================= gemm kernel: standalone ==============================================
__global__ __launch_bounds__(256, 2) void gemm_kernel(const int* __restrict__ cats,
                                                      const float* __restrict__ charges,
                                                      const float* __restrict__ nmask,
                                                      const u16* __restrict__ embp,
                                                      const u16* __restrict__ Wt,
                                                      const float* __restrict__ bias,
                                                      float* __restrict__ out) {
    __shared__ u16 h_lds[64][DIM + 8];           // 33.8 KB
    const int gb = blockIdx.x;
    const int tid = threadIdx.x;
    const int m0 = gb * 64;

    // Stage h tile (64 rows x 256 cols) bf16: thread -> (row, 64-col quarter)
    {
        int r = tid >> 2;
        int q = tid & 3;
        int m = m0 + r;
        float mask = nmask[m];
        const uint4* src = (const uint4*)(embp + (size_t)cats[m] * 256 + q * 64);
        uint4 v[8];
        #pragma unroll
        for (int t = 0; t < 8; ++t) v[t] = src[t];
        if (mask != 1.0f) {                 // general path: unpack * mask * repack
            #pragma unroll
            for (int t = 0; t < 8; ++t) {
                u32* w = (u32*)&v[t];
                #pragma unroll
                for (int j = 0; j < 4; ++j) {
                    u16 lo = f2bf(bf2f((u16)(w[j] & 0xFFFF)) * mask);
                    u16 hi = f2bf(bf2f((u16)(w[j] >> 16)) * mask);
                    w[j] = (u32)lo | ((u32)hi << 16);
                }
            }
        }
        if (q == 0) {                       // h col 0 = charge * mask
            u32* w0 = (u32*)&v[0];
            w0[0] = (w0[0] & 0xFFFF0000u) | (u32)f2bf(charges[m] * mask);
        }
        #pragma unroll
        for (int t = 0; t < 8; ++t)
            *(uint4*)&h_lds[r][q * 64 + t * 8] = v[t];
    }
    __syncthreads();

    const int wave = tid >> 6;
    const int lane = tid & 63;
    const int lrow = lane & 15;   // A row / B col / D col
    const int quad = lane >> 4;   // k-group for A/B, row-group for D
    const int nbase = wave * 128;

    f32x4 acc[4][8];
    #pragma unroll
    for (int ms = 0; ms < 4; ++ms)
        #pragma unroll
        for (int nt = 0; nt < 8; ++nt) acc[ms][nt] = (f32x4)(0.0f);

    #pragma unroll
    for (int k0 = 0; k0 < DIM; k0 += 32) {
        bf16x8 a[4];
        #pragma unroll
        for (int ms = 0; ms < 4; ++ms)
            a[ms] = *(const bf16x8*)&h_lds[ms * 16 + lrow][k0 + quad * 8];
        #pragma unroll
        for (int nt = 0; nt < 8; ++nt) {
            bf16x8 bfr = *(const bf16x8*)&Wt[(size_t)(nbase + nt * 16 + lrow) * DIM + k0 + quad * 8];
            #pragma unroll
            for (int ms = 0; ms < 4; ++ms)
                acc[ms][nt] = __builtin_amdgcn_mfma_f32_16x16x32_bf16(a[ms], bfr, acc[ms][nt], 0, 0, 0);
        }
    }

    // Epilogue: D[row=quad*4+r][col=lrow] per 16x16 tile; + bias, nontemporal fp32 store
    #pragma unroll
    for (int nt = 0; nt < 8; ++nt) {
        int n = nbase + nt * 16 + lrow;
        float bv = bias[n];
        #pragma unroll
        for (int ms = 0; ms < 4; ++ms)
            #pragma unroll
            for (int r = 0; r < 4; ++r)
                __builtin_nontemporal_store(acc[ms][nt][r] + bv,
                    out + (size_t)(m0 + ms * 16 + quad * 4 + r) * NOUT + n);
    }
}

extern "C" void kernel_launch(void* const* d_in, const int* in_sizes, int n_in,
                              void* d_out, int out_size, void* d_ws, size_t ws_size,
                              hipStream_t stream) {
    const float* x       = (const float*)d_in[0];   // [32768*3] fp32
    const int*   cats    = (const int*)d_in[1];     // [32768] int32
    const float* charges = (const float*)d_in[2];   // [32768] fp32
    const int*   edges   = (const int*)d_in[3];     // [2*E] int32
    const float* nmask   = (const float*)d_in[4];   // [32768] fp32 (all ones)
    // d_in[5] edge_mask: unused by reference
    const float* emb     = (const float*)d_in[6];   // [100*255] fp32
    const float* W       = (const float*)d_in[7];   // [256*512] fp32
    const float* bias    = (const float*)d_in[8];   // [512] fp32

    float* out    = (float*)d_out;
    float* params = out;                          // 16,777,216 fp32
    float* radial = out + PARAM_SZ;               // 4,194,304 fp32
    float* cd     = out + PARAM_SZ + NEDGE;       // 12,582,912 fp32

    // d_ws layout: Wt 256KB | xp 512KB | embp 51.2KB  (~820KB total)
    u16*    Wt   = (u16*)d_ws;
    float4* xp   = (float4*)((char*)d_ws + 256 * 1024);
    u16*    embp = (u16*)((char*)d_ws + 768 * 1024);

    prep_kernel<<<356, 256, 0, stream>>>(W, x, emb, Wt, xp, embp);
    edge_kernel<<<EDGE_BLOCKS, 256, 0, stream>>>(edges, xp, radial, cd);
    gemm_kernel<<<GEMM_BLOCKS, 256, 0, stream>>>(cats, charges, nmask, embp, Wt, bias, params);
}

// Round 5
// 232.139 us; speedup vs baseline: 1.0149x; 1.0149x over previous
//
#include <hip/hip_runtime.h>

typedef unsigned short u16;
typedef unsigned int u32;
typedef __attribute__((ext_vector_type(8))) short bf16x8;
typedef __attribute__((ext_vector_type(4))) float f32x4;

#define DIM 256
#define NOUT 512
#define MROWS 32768
#define NNODE 32768
#define NEDGE (256*128*128)
#define PARAM_SZ (32768*512)
#define GEMM_BLOCKS 512            // MROWS / 64  (64x128 wave tile)
#define EDGE_BLOCKS 2048           // NEDGE / 2048 (8 edges/thread)

__device__ __forceinline__ u16 f2bf(float f) {
    u32 x = __float_as_uint(f);
    u32 r = (x + 0x7FFFu + ((x >> 16) & 1u)) >> 16;   // round-to-nearest-even
    return (u16)r;
}
__device__ __forceinline__ float bf2f(u16 u) {
    union { u32 i; float f; } v; v.i = ((u32)u) << 16; return v.f;
}

// ================= prep: Wt transpose + x float4-pack + emb bf16-pad, one dispatch =======
__global__ __launch_bounds__(256) void prep_kernel(const float* __restrict__ W,
                                                   const float* __restrict__ x,
                                                   const float* __restrict__ emb,
                                                   u16* __restrict__ Wt,
                                                   float4* __restrict__ xp,
                                                   u16* __restrict__ embp) {
    const int b = blockIdx.x;
    const int tid = threadIdx.x;
    if (b < 128) {
        __shared__ u16 tile[32][33];
        int k0 = (b >> 4) * 32;            // K: 256 -> 8
        int n0 = (b & 15) * 32;            // N: 512 -> 16
        int tx = tid & 31, ty0 = tid >> 5; // 8 rows/pass, 4 passes
        #pragma unroll
        for (int j = 0; j < 4; ++j) {
            int ty = ty0 + j * 8;
            tile[ty][tx] = f2bf(W[(k0 + ty) * NOUT + n0 + tx]);
        }
        __syncthreads();
        #pragma unroll
        for (int j = 0; j < 4; ++j) {
            int ty = ty0 + j * 8;
            Wt[(n0 + ty) * DIM + k0 + tx] = tile[tx][ty];
        }
    } else if (b < 256) {
        int i = (b - 128) * 256 + tid;     // 32768 nodes
        float4 v;
        v.x = x[i * 3 + 0]; v.y = x[i * 3 + 1]; v.z = x[i * 3 + 2]; v.w = 0.0f;
        xp[i] = v;
    } else {
        int i = (b - 256) * 256 + tid;     // 100*256 = 25600 entries
        int col = i & 255;
        int row = i >> 8;
        embp[i] = (col == 0) ? (u16)0 : f2bf(emb[row * 255 + col - 1]);
    }
}

// ================= edge path: 8 edges/thread, 16 plain gathers in flight ================
// MLP test: no asm, no sc0, no batched vmcnt(0) -- compiler issues all 16 dwordx4
// gathers before first use and drains progressively.  LDS buf = 6144 floats (24 KB).
__device__ __forceinline__ void edge_part(int eb, int tid,
                                          const int* __restrict__ edges,
                                          const f32x4* __restrict__ xp,
                                          float* __restrict__ radial_out,
                                          float* __restrict__ cd_out,
                                          float* buf) {
    // two int4-groups per thread: edges [eb*2048 + g*1024 + tid*4 ...]
    const int t4a = eb * 512 + tid;
    const int t4b = t4a + 256;
    int4 ra = ((const int4*)edges)[t4a];
    int4 rb = ((const int4*)edges)[t4b];
    int4 ca = ((const int4*)(edges + NEDGE))[t4a];
    int4 cb = ((const int4*)(edges + NEDGE))[t4b];

    // 16 independent gathers
    f32x4 xra0 = xp[ra.x], xra1 = xp[ra.y], xra2 = xp[ra.z], xra3 = xp[ra.w];
    f32x4 xrb0 = xp[rb.x], xrb1 = xp[rb.y], xrb2 = xp[rb.z], xrb3 = xp[rb.w];
    f32x4 xca0 = xp[ca.x], xca1 = xp[ca.y], xca2 = xp[ca.z], xca3 = xp[ca.w];
    f32x4 xcb0 = xp[cb.x], xcb1 = xp[cb.y], xcb2 = xp[cb.z], xcb3 = xp[cb.w];

    f32x4 rada, radb;
    float cdva[12], cdvb[12];
    #pragma unroll
    for (int e = 0; e < 4; ++e) {
        f32x4 a = (e == 0) ? xra0 : (e == 1) ? xra1 : (e == 2) ? xra2 : xra3;
        f32x4 b = (e == 0) ? xca0 : (e == 1) ? xca1 : (e == 2) ? xca2 : xca3;
        float dx = a.x - b.x, dy = a.y - b.y, dz = a.z - b.z;
        float r = dx * dx + dy * dy + dz * dz;
        float inv = 1.0f / (sqrtf(r + 1e-8f) + 1.0f);   // norm + norm_constant(1.0)
        rada[e] = r;
        cdva[e * 3 + 0] = dx * inv;
        cdva[e * 3 + 1] = dy * inv;
        cdva[e * 3 + 2] = dz * inv;
    }
    #pragma unroll
    for (int e = 0; e < 4; ++e) {
        f32x4 a = (e == 0) ? xrb0 : (e == 1) ? xrb1 : (e == 2) ? xrb2 : xrb3;
        f32x4 b = (e == 0) ? xcb0 : (e == 1) ? xcb1 : (e == 2) ? xcb2 : xcb3;
        float dx = a.x - b.x, dy = a.y - b.y, dz = a.z - b.z;
        float r = dx * dx + dy * dy + dz * dz;
        float inv = 1.0f / (sqrtf(r + 1e-8f) + 1.0f);
        radb[e] = r;
        cdvb[e * 3 + 0] = dx * inv;
        cdvb[e * 3 + 1] = dy * inv;
        cdvb[e * 3 + 2] = dz * inv;
    }
    __builtin_nontemporal_store(rada, ((f32x4*)radial_out) + t4a);
    __builtin_nontemporal_store(radb, ((f32x4*)radial_out) + t4b);

    // repack coord_diff [2048,3] through LDS -> dense f32x4 global stores
    // group g edges' cd floats start at global f32x4 slot eb*1536 + g*768 + tid*3
    #pragma unroll
    for (int k = 0; k < 3; ++k) {
        ((f32x4*)buf)[tid * 3 + k]       = ((const f32x4*)cdva)[k];
        ((f32x4*)buf)[768 + tid * 3 + k] = ((const f32x4*)cdvb)[k];
    }
    __syncthreads();
    f32x4* cdg = (f32x4*)(cd_out + (size_t)eb * 6144);
    #pragma unroll
    for (int k = 0; k < 6; ++k)
        __builtin_nontemporal_store(((const f32x4*)buf)[k * 256 + tid], cdg + k * 256 + tid);
}

__device__ __forceinline__ void gemm_part(int gb, int tid,
                                          const int* __restrict__ cats,
                                          const float* __restrict__ charges,
                                          const float* __restrict__ nmask,
                                          const u16* __restrict__ embp,
                                          const u16* __restrict__ Wt,
                                          const float* __restrict__ bias,
                                          float* __restrict__ out,
                                          u16 (*h_lds)[DIM + 8]) {
    const int m0 = gb * 64;

    // Stage h tile (64 rows x 256 cols) bf16: thread -> (row, 64-col quarter)
    {
        int r = tid >> 2;
        int q = tid & 3;
        int m = m0 + r;
        float mask = nmask[m];
        const uint4* src = (const uint4*)(embp + (size_t)cats[m] * 256 + q * 64);
        uint4 v[8];
        #pragma unroll
        for (int t = 0; t < 8; ++t) v[t] = src[t];
        if (mask != 1.0f) {                 // general path: unpack * mask * repack
            #pragma unroll
            for (int t = 0; t < 8; ++t) {
                u32* w = (u32*)&v[t];
                #pragma unroll
                for (int j = 0; j < 4; ++j) {
                    u16 lo = f2bf(bf2f((u16)(w[j] & 0xFFFF)) * mask);
                    u16 hi = f2bf(bf2f((u16)(w[j] >> 16)) * mask);
                    w[j] = (u32)lo | ((u32)hi << 16);
                }
            }
        }
        if (q == 0) {                       // h col 0 = charge * mask
            u32* w0 = (u32*)&v[0];
            w0[0] = (w0[0] & 0xFFFF0000u) | (u32)f2bf(charges[m] * mask);
        }
        #pragma unroll
        for (int t = 0; t < 8; ++t)
            *(uint4*)&h_lds[r][q * 64 + t * 8] = v[t];
    }
    __syncthreads();

    const int wave = tid >> 6;
    const int lane = tid & 63;
    const int lrow = lane & 15;   // A row / B col / D col
    const int quad = lane >> 4;   // k-group for A/B, row-group for D
    const int nbase = wave * 128;

    f32x4 acc[4][8];
    #pragma unroll
    for (int ms = 0; ms < 4; ++ms)
        #pragma unroll
        for (int nt = 0; nt < 8; ++nt) acc[ms][nt] = (f32x4)(0.0f);

    #pragma unroll
    for (int k0 = 0; k0 < DIM; k0 += 32) {
        bf16x8 a[4];
        #pragma unroll
        for (int ms = 0; ms < 4; ++ms)
            a[ms] = *(const bf16x8*)&h_lds[ms * 16 + lrow][k0 + quad * 8];
        #pragma unroll
        for (int nt = 0; nt < 8; ++nt) {
            bf16x8 bfr = *(const bf16x8*)&Wt[(size_t)(nbase + nt * 16 + lrow) * DIM + k0 + quad * 8];
            #pragma unroll
            for (int ms = 0; ms < 4; ++ms)
                acc[ms][nt] = __builtin_amdgcn_mfma_f32_16x16x32_bf16(a[ms], bfr, acc[ms][nt], 0, 0, 0);
        }
    }

    // Epilogue: D[row=quad*4+r][col=lrow] per 16x16 tile; + bias, nontemporal fp32 store
    #pragma unroll
    for (int nt = 0; nt < 8; ++nt) {
        int n = nbase + nt * 16 + lrow;
        float bv = bias[n];
        #pragma unroll
        for (int ms = 0; ms < 4; ++ms)
            #pragma unroll
            for (int r = 0; r < 4; ++r)
                __builtin_nontemporal_store(acc[ms][nt][r] + bv,
                    out + (size_t)(m0 + ms * 16 + quad * 4 + r) * NOUT + n);
    }
}

__global__ __launch_bounds__(256, 2) void main_kernel(const int* __restrict__ cats,
                                                      const float* __restrict__ charges,
                                                      const float* __restrict__ nmask,
                                                      const u16* __restrict__ embp,
                                                      const u16* __restrict__ Wt,
                                                      const float* __restrict__ bias,
                                                      const int* __restrict__ edges,
                                                      const float4* __restrict__ xp,
                                                      float* __restrict__ params,
                                                      float* __restrict__ radial,
                                                      float* __restrict__ cd) {
    __shared__ char smem[64 * (DIM + 8) * sizeof(u16)];   // 33.8 KB, union of both paths
    if (blockIdx.x < GEMM_BLOCKS)
        gemm_part(blockIdx.x, threadIdx.x, cats, charges, nmask, embp, Wt, bias, params,
                  (u16 (*)[DIM + 8])smem);
    else
        edge_part(blockIdx.x - GEMM_BLOCKS, threadIdx.x, edges, (const f32x4*)xp,
                  radial, cd, (float*)smem);
}

extern "C" void kernel_launch(void* const* d_in, const int* in_sizes, int n_in,
                              void* d_out, int out_size, void* d_ws, size_t ws_size,
                              hipStream_t stream) {
    const float* x       = (const float*)d_in[0];   // [32768*3] fp32
    const int*   cats    = (const int*)d_in[1];     // [32768] int32
    const float* charges = (const float*)d_in[2];   // [32768] fp32
    const int*   edges   = (const int*)d_in[3];     // [2*E] int32
    const float* nmask   = (const float*)d_in[4];   // [32768] fp32 (all ones)
    // d_in[5] edge_mask: unused by reference
    const float* emb     = (const float*)d_in[6];   // [100*255] fp32
    const float* W       = (const float*)d_in[7];   // [256*512] fp32
    const float* bias    = (const float*)d_in[8];   // [512] fp32

    float* out    = (float*)d_out;
    float* params = out;                          // 16,777,216 fp32
    float* radial = out + PARAM_SZ;               // 4,194,304 fp32
    float* cd     = out + PARAM_SZ + NEDGE;       // 12,582,912 fp32

    // d_ws layout: Wt 256KB | xp 512KB | embp 51.2KB  (~820KB total)
    u16*    Wt   = (u16*)d_ws;
    float4* xp   = (float4*)((char*)d_ws + 256 * 1024);
    u16*    embp = (u16*)((char*)d_ws + 768 * 1024);

    prep_kernel<<<356, 256, 0, stream>>>(W, x, emb, Wt, xp, embp);
    main_kernel<<<GEMM_BLOCKS + EDGE_BLOCKS, 256, 0, stream>>>(
        cats, charges, nmask, embp, Wt, bias, edges, xp, params, radial, cd);
}